// Round 9
// baseline (194.249 us; speedup 1.0000x reference)
//
#include <hip/hip_runtime.h>

// ---------------------------------------------------------------------------
// NearestSim: out[t] = -cos(q_t, items[argmax_j q_t . items_j])
// T=16384, M=4096, C=512, fp32 in/out.
// fp16 MFMA fused GEMM + packed (score|idx) top-2, exact fp32 rescue.
// R9: (1) XOR-swizzled LDS image -> conflict-free b128 fragment reads
//     (R7 paid exactly 4 cyc/read: 1.05e7 conflict cyc / 2.62M reads);
//     (2) square 64x64 wave tile: 8 reads/kk vs 10, same 64-AGPR acc;
//     (3) 12-bit global item idx packed into score mantissa low bits
//     (quantization <=0.03 abs vs top1-top2 gap ~5.5 -> provably harmless;
//     any flip it causes is between items whose cosines agree to ~1e-4).
// ---------------------------------------------------------------------------

#define TQ 16384
#define MI 4096
#define CD 512
#define NSPLIT 32
#define BM 128          // block query rows (2 wy-halves x 64)
#define BN 128          // block item cols (2 wx-halves x 64)
#define KITER (CD / 32) // 16 k-steps of 32

typedef _Float16 half8   __attribute__((ext_vector_type(8)));
typedef _Float16 half4_t __attribute__((ext_vector_type(4)));
typedef float    float4t __attribute__((ext_vector_type(4)));

// workspace layout (bytes)
#define QH_OFF   (0u)
#define QH_BYTES ((unsigned)TQ * CD * 2u)          // 16 MB fp16 queries
#define IH_OFF   (QH_OFF + QH_BYTES)
#define IH_BYTES ((unsigned)MI * CD * 2u)          // 4 MB fp16 items
#define PART_OFF (IH_OFF + IH_BYTES)
#define PART_BYTES ((unsigned)TQ * 64u * 8u)       // 8 MB: 64 float2 / query
// total 28 MB (same proven footprint as R4/R6/R7)

__device__ __forceinline__ void lds_load16(const void* g, void* l) {
  __builtin_amdgcn_global_load_lds(
      (const __attribute__((address_space(1))) void*)g,
      (__attribute__((address_space(3))) void*)l, 16, 0, 0);
}

// ---------------- kernel 1: fp32 -> fp16 conversion (row-major) -------------
__global__ __launch_bounds__(256) void convert_kernel(
    const float* __restrict__ q, const float* __restrict__ it,
    char* __restrict__ ws) {
  int idx = blockIdx.x * 256 + threadIdx.x;
  const int QV = TQ * CD / 4;
  const int IV = MI * CD / 4;
  half4_t* Qh = (half4_t*)(ws + QH_OFF);
  half4_t* Ih = (half4_t*)(ws + IH_OFF);
  if (idx < QV) {
    float4 v = ((const float4*)q)[idx];
    half4_t h = {(_Float16)v.x, (_Float16)v.y, (_Float16)v.z, (_Float16)v.w};
    Qh[idx] = h;
  }
  if (idx < IV) {
    float4 v = ((const float4*)it)[idx];
    half4_t h = {(_Float16)v.x, (_Float16)v.y, (_Float16)v.z, (_Float16)v.w};
    Ih[idx] = h;
  }
}

// ---------------- kernel 2: fused fp16 GEMM + packed top-2 ------------------
// grid (TQ/BM, NSPLIT), block 256 = 2x2 waves; wave tile 64q x 64i
// (4x4 grid of 16x16x32 MFMAs, 64 AGPR acc). Double-buffered staging,
// 1 barrier per kk, 3 blocks/CU.
// LDS image: phys(row, chunk16) = row*64 + ((chunk ^ ((row>>1)&3))*16)
// -> each consecutive-8-lane b128 phase covers all 8 bank-granule classes.
__global__ __launch_bounds__(256, 3) void score_kernel(char* __restrict__ ws) {
  __shared__ __align__(16) char sA[2][BM * 64];  // 2 x 8 KB
  __shared__ __align__(16) char sB[2][BN * 64];  // 2 x 8 KB  (total 32 KB)

  const int tid  = threadIdx.x;
  const int lane = tid & 63;
  const int wave = tid >> 6;
  const int quad = lane >> 4;
  const int l15  = lane & 15;
  const int wy   = wave >> 1;   // 0..1 : query half
  const int wx   = wave & 1;    // 0..1 : item half
  const int qtile = blockIdx.x;
  const int split = blockIdx.y;

  const char* Qh = ws + QH_OFF;
  const char* Ih = ws + IH_OFF;

  // staging: thread t stages the gmem chunk that lands at phys t*16 (+h*4096):
  // row = h*64 + (t>>2), phys chunk = t&3, logical chunk = (t&3)^((t>>3)&3).
  const int qlog = (tid & 3) ^ ((tid >> 3) & 3);
  const int f = (tid >> 2) * 1024 + qlog * 16;           // gmem offset pattern
  const char* gA0 = Qh + (size_t)qtile * BM * 1024 + f;  // q rows 0..63
  const char* gA1 = gA0 + 64 * 1024;                     // q rows 64..127
  const char* gB0 = Ih + (size_t)split * BN * 1024 + f;  // item rows 0..63
  const char* gB1 = gB0 + 64 * 1024;                     // item rows 64..127
  const int flat = tid * 16;  // LDS dest (wave-uniform base + lane*16)

  // fragment offsets: row = {wy|wx}*64 + mi*16 + l15; swizzle uses (l15>>1)&3
  const int swz = (l15 >> 1) & 3;
  const int aBase = (wy * 64 + l15) * 64 + ((quad ^ swz) * 16);  // + mi*1024
  const int bBase = (wx * 64 + l15) * 64 + ((quad ^ swz) * 16);  // + ni*1024

  float4t acc[4][4];
#pragma unroll
  for (int mi = 0; mi < 4; ++mi)
#pragma unroll
    for (int ni = 0; ni < 4; ++ni) acc[mi][ni] = (float4t){0.f, 0.f, 0.f, 0.f};

  // preload kk=0 into buffer 0
  lds_load16(gA0, sA[0] + flat);
  lds_load16(gA1, sA[0] + flat + 4096);
  lds_load16(gB0, sB[0] + flat);
  lds_load16(gB1, sB[0] + flat + 4096);

#pragma unroll
  for (int kk = 0; kk < KITER; ++kk) {
    const int cur = kk & 1;
    const int nxt = cur ^ 1;
    // barrier: staging of kk drained (compiler vmcnt(0)); buf[nxt] free.
    __syncthreads();

    // prefetch kk+1; delivery overlaps kk's ds_reads + MFMAs.
    if (kk + 1 < KITER) {
      const int kb = (kk + 1) * 64;
      lds_load16(gA0 + kb, sA[nxt] + flat);
      lds_load16(gA1 + kb, sA[nxt] + flat + 4096);
      lds_load16(gB0 + kb, sB[nxt] + flat);
      lds_load16(gB1 + kb, sB[nxt] + flat + 4096);
    }

    half8 a[4], b[4];
#pragma unroll
    for (int mi = 0; mi < 4; ++mi)
      a[mi] = *(const half8*)(sA[cur] + aBase + mi * 1024);
#pragma unroll
    for (int ni = 0; ni < 4; ++ni)
      b[ni] = *(const half8*)(sB[cur] + bBase + ni * 1024);
#pragma unroll
    for (int mi = 0; mi < 4; ++mi)
#pragma unroll
      for (int ni = 0; ni < 4; ++ni)
        acc[mi][ni] = __builtin_amdgcn_mfma_f32_16x16x32_f16(
            a[mi], b[ni], acc[mi][ni], 0, 0, 0);
  }

  // ---- epilogue: packed (score | global idx) top-2, per query row ----
  // C row = quad*4+r, col = l15. Global item = split*128+wx*64+ni*16+l15
  // fits 12 bits; quantizing score to 2^12 ulp (<=0.03 abs) is harmless.
  float t1[16], t2[16];
#pragma unroll
  for (int s = 0; s < 16; ++s) { t1[s] = -1e30f; t2[s] = -1e30f; }

  const int locBase = split * 128 + wx * 64 + l15;
#pragma unroll
  for (int ni = 0; ni < 4; ++ni) {
    const int loc = locBase + ni * 16;
#pragma unroll
    for (int mi = 0; mi < 4; ++mi) {
#pragma unroll
      for (int r = 0; r < 4; ++r) {
        const int s = mi * 4 + r;
        const int pb = (__float_as_int(acc[mi][ni][r]) & 0xFFFFF000) | loc;
        const float pv = __int_as_float(pb);
        const float mn = fminf(t1[s], pv);
        t1[s] = fmaxf(t1[s], pv);
        t2[s] = fmaxf(t2[s], mn);
      }
    }
  }

  // 4-step butterfly across the 16-lane l15 group (pure fmin/fmax)
#pragma unroll
  for (int s = 0; s < 16; ++s) {
#pragma unroll
    for (int m = 1; m < 16; m <<= 1) {
      const float o1 = __shfl_xor(t1[s], m, 16);
      const float o2 = __shfl_xor(t2[s], m, 16);
      const float mn = fminf(t1[s], o1);
      t1[s] = fmaxf(t1[s], o1);
      t2[s] = fmaxf(fmaxf(t2[s], o2), mn);
    }
  }

  // writer: l15 == 0; entry = split*2 + wx (64 entries per query)
  if (l15 == 0) {
    float2* part = (float2*)(ws + PART_OFF);
    const int e = split * 2 + wx;
#pragma unroll
    for (int s = 0; s < 16; ++s) {
      const int qrow = qtile * BM + wy * 64 + (s >> 2) * 16 + quad * 4 + (s & 3);
      part[(size_t)qrow * 64 + e] = make_float2(t1[s], t2[s]);
    }
  }
}

// ---------------- kernel 3: merge partials + exact fp32 rescue --------------
// one wave per query: 64 packed entries (1/lane) -> global fp16 top-2 ->
// exact fp32 re-score of both candidates from the ORIGINAL fp32 inputs.
__global__ __launch_bounds__(256) void rescue_kernel(
    const float* __restrict__ q, const float* __restrict__ items,
    const char* __restrict__ ws, float* __restrict__ out) {
  const int wave = threadIdx.x >> 6;
  const int lane = threadIdx.x & 63;
  const int qrow = blockIdx.x * 4 + wave;

  const float2* part = (const float2*)(ws + PART_OFF);
  float2 ent = part[(size_t)qrow * 64 + lane];  // coalesced 512B burst
  float t1 = ent.x, t2 = ent.y;

#pragma unroll
  for (int m = 1; m < 64; m <<= 1) {
    const float o1 = __shfl_xor(t1, m, 64);
    const float o2 = __shfl_xor(t2, m, 64);
    const float mn = fminf(t1, o1);
    t1 = fmaxf(t1, o1);
    t2 = fmaxf(fmaxf(t2, o2), mn);
  }
  const int c1i = __float_as_int(t1) & 0xFFF;
  const int c2i = __float_as_int(t2) & 0xFFF;

  const float4* qp = (const float4*)(q + (size_t)qrow * CD);
  const float4* p1 = (const float4*)(items + (size_t)c1i * CD);
  const float4* p2 = (const float4*)(items + (size_t)c2i * CD);
  float4 qa = qp[lane * 2], qb = qp[lane * 2 + 1];
  float4 xa = p1[lane * 2], xb = p1[lane * 2 + 1];
  float4 ya = p2[lane * 2], yb = p2[lane * 2 + 1];

  float d1 = qa.x * xa.x + qa.y * xa.y + qa.z * xa.z + qa.w * xa.w +
             qb.x * xb.x + qb.y * xb.y + qb.z * xb.z + qb.w * xb.w;
  float d2 = qa.x * ya.x + qa.y * ya.y + qa.z * ya.z + qa.w * ya.w +
             qb.x * yb.x + qb.y * yb.y + qb.z * yb.z + qb.w * yb.w;
  float qq = qa.x * qa.x + qa.y * qa.y + qa.z * qa.z + qa.w * qa.w +
             qb.x * qb.x + qb.y * qb.y + qb.z * qb.z + qb.w * qb.w;
  float i1 = xa.x * xa.x + xa.y * xa.y + xa.z * xa.z + xa.w * xa.w +
             xb.x * xb.x + xb.y * xb.y + xb.z * xb.z + xb.w * xb.w;
  float i2 = ya.x * ya.x + ya.y * ya.y + ya.z * ya.z + ya.w * ya.w +
             yb.x * yb.x + yb.y * yb.y + yb.z * yb.z + yb.w * yb.w;

#pragma unroll
  for (int m = 1; m < 64; m <<= 1) {
    d1 += __shfl_xor(d1, m, 64);
    d2 += __shfl_xor(d2, m, 64);
    qq += __shfl_xor(qq, m, 64);
    i1 += __shfl_xor(i1, m, 64);
    i2 += __shfl_xor(i2, m, 64);
  }

  if (lane == 0) {
    bool use2 = (d2 > d1) || (d2 == d1 && c2i < c1i);
    float d  = use2 ? d2 : d1;
    float nn = use2 ? i2 : i1;
    float nq = fmaxf(sqrtf(qq), 1e-12f);
    float np = fmaxf(sqrtf(nn), 1e-12f);
    out[qrow] = -(d / (nq * np));
  }
}

// ---------------------------------------------------------------------------
extern "C" void kernel_launch(void* const* d_in, const int* in_sizes, int n_in,
                              void* d_out, int out_size, void* d_ws,
                              size_t ws_size, hipStream_t stream) {
  const float* q  = (const float*)d_in[0];
  const float* it = (const float*)d_in[1];
  char* ws = (char*)d_ws;
  float* out = (float*)d_out;

  convert_kernel<<<TQ * CD / 4 / 256, 256, 0, stream>>>(q, it, ws);
  dim3 grid(TQ / BM, NSPLIT);
  score_kernel<<<grid, 256, 0, stream>>>(ws);
  rescue_kernel<<<TQ / 4, 256, 0, stream>>>(q, it, ws, out);
}